// Round 3
// baseline (211.252 us; speedup 1.0000x reference)
//
#include <hip/hip_runtime.h>

// YOLO v1 loss, B=16384, S=7, C=30. 192.7 MB read -> 1 float.
// Layout: pred[((b*S+i)*S+j)*30 + c]; i -> gi (x offset), j -> gj (y offset).
//
// v3: v2's LDS staging was a null result (72 us invariant, 1.33 TB/s HBM) ->
// bottleneck is structural, not coalescing. This version:
//  - 2 cells/thread: 60 floats = 15 aligned float4 per array, all 30 loads
//    issued up front (480 B/lane in flight, 4x v0's MLP), register-only.
//  - grid 3136 -> 1568 blocks (halves per-wg dispatch + per-block overhead).
//  - NO same-address atomicAdd hot-spot: per-block partials to workspace,
//    1-block reduce kernel produces the scalar (replaces zero_out; still 2
//    dispatches total). Atomic fallback kept for tiny-workspace safety.

#define NS 7
#define NC 30
#define BLOCK 256
#define NPAIRS 401408               // 802816 cells / 2
#define GRID (NPAIRS / BLOCK)       // 1568 exact, no partial blocks

__global__ void zero_out_kernel(float* out) { out[0] = 0.0f; }

__device__ __forceinline__ float cell_loss(const float* __restrict__ p,
                                           const float* __restrict__ t,
                                           float gi, float gj)
{
    const float STEP = 1.0f / 7.0f;
    const float L_COORD = 5.0f;
    const float L_NOOBJ = 0.5f;

    // _convert_box for target, pred box1 (ch 0:4), pred box2 (ch 5:9)
    float ta, tb, tc, td;
    {
        float cx = (t[0] + gi) * STEP;
        float cy = (t[1] + gj) * STEP;
        ta = fmaxf(cx - t[2] * 0.5f, 0.0f);
        tb = fmaxf(cy - t[3] * 0.5f, 0.0f);
        tc = fminf(cx + t[2] * 0.5f, 1.0f);
        td = fminf(cy + t[3] * 0.5f, 1.0f);
    }
    float q1, w1, e1, r1;
    {
        float cx = (p[0] + gi) * STEP;
        float cy = (p[1] + gj) * STEP;
        q1 = fmaxf(cx - p[2] * 0.5f, 0.0f);
        w1 = fmaxf(cy - p[3] * 0.5f, 0.0f);
        e1 = fminf(cx + p[2] * 0.5f, 1.0f);
        r1 = fminf(cy + p[3] * 0.5f, 1.0f);
    }
    float q2, w2, e2, r2;
    {
        float cx = (p[5] + gi) * STEP;
        float cy = (p[6] + gj) * STEP;
        q2 = fmaxf(cx - p[7] * 0.5f, 0.0f);
        w2 = fmaxf(cy - p[8] * 0.5f, 0.0f);
        e2 = fminf(cx + p[7] * 0.5f, 1.0f);
        r2 = fminf(cy + p[8] * 0.5f, 1.0f);
    }

    float tarea = (td - tb) * (tc - ta);
    // _iou(tbox, pbox): inter NOT clamped; iou = inter>0 ? inter/(union+1e-5) : 0
    float iou1, iou2;
    {
        float minx = fmaxf(ta, q1), miny = fmaxf(tb, w1);
        float maxx = fminf(tc, e1), maxy = fminf(td, r1);
        float inter = (maxy - miny) * (maxx - minx);
        float uni = (e1 - q1) * (r1 - w1) + tarea - inter;
        iou1 = (inter > 0.0f) ? inter / (uni + 1e-5f) : 0.0f;
    }
    {
        float minx = fmaxf(ta, q2), miny = fmaxf(tb, w2);
        float maxx = fminf(tc, e2), maxy = fminf(td, r2);
        float inter = (maxy - miny) * (maxx - minx);
        float uni = (e2 - q2) * (r2 - w2) + tarea - inter;
        iou2 = (inter > 0.0f) ? inter / (uni + 1e-5f) : 0.0f;
    }

    bool sel2 = (iou1 <= iou2);
    float conf_t = sel2 ? iou2 : iou1;
    float px = sel2 ? p[5] : p[0];
    float py = sel2 ? p[6] : p[1];
    float pw = sel2 ? p[7] : p[2];
    float ph = sel2 ? p[8] : p[3];
    float pconf = sel2 ? p[9] : p[4];

    float obj = (t[4] > 0.0f) ? 1.0f : 0.0f;
    float noobj = (t[4] == 0.0f) ? 1.0f : 0.0f;

    float dx = px - t[0], dy = py - t[1];
    float dw = pw - t[2], dh = ph - t[3];
    float coord = dx * dx + dy * dy + dw * dw + dh * dh;

    float dc = pconf - conf_t;
    float obj_loss = dc * dc;

    float cls = 0.0f;
    #pragma unroll
    for (int k = 10; k < NC; ++k) {
        float d = p[k] - t[k];
        cls += d * d;
    }

    float d4 = p[4] - t[4];
    float d9 = p[9] - t[9];
    float noobj_loss = d4 * d4 + d9 * d9;

    return obj * (obj_loss + L_COORD * coord + cls) + L_NOOBJ * noobj * noobj_loss;
}

__global__ __launch_bounds__(BLOCK) void yolo_loss_main(
    const float* __restrict__ pred,
    const float* __restrict__ targ,
    float* __restrict__ partial,
    float* __restrict__ out,
    int atomic_mode, float inv_B)
{
    const int tid = threadIdx.x;
    const int u = blockIdx.x * BLOCK + tid;   // pair index, NPAIRS total (exact)

    // ---- issue all 30 float4 loads up front (static-indexed register arrays) ----
    float fp[60], ft[60];
    const float4* pg = (const float4*)pred + (size_t)u * 15;
    const float4* tg = (const float4*)targ + (size_t)u * 15;
    #pragma unroll
    for (int k = 0; k < 15; ++k) {
        float4 v = pg[k];
        fp[4 * k] = v.x; fp[4 * k + 1] = v.y; fp[4 * k + 2] = v.z; fp[4 * k + 3] = v.w;
    }
    #pragma unroll
    for (int k = 0; k < 15; ++k) {
        float4 v = tg[k];
        ft[4 * k] = v.x; ft[4 * k + 1] = v.y; ft[4 * k + 2] = v.z; ft[4 * k + 3] = v.w;
    }

    const int cellA = 2 * u;
    const int cellB = 2 * u + 1;
    const int jA = cellA % NS, iA = (cellA / NS) % NS;
    const int jB = cellB % NS, iB = (cellB / NS) % NS;

    float lsum = cell_loss(fp, ft, (float)iA, (float)jA)
               + cell_loss(fp + 30, ft + 30, (float)iB, (float)jB);

    // wave(64) shuffle reduce
    #pragma unroll
    for (int off = 32; off > 0; off >>= 1)
        lsum += __shfl_down(lsum, off, 64);

    __shared__ float wsum[4];
    int lane = tid & 63;
    int wid = tid >> 6;
    if (lane == 0) wsum[wid] = lsum;
    __syncthreads();
    if (tid == 0) {
        float s = (wsum[0] + wsum[1]) + (wsum[2] + wsum[3]);
        if (atomic_mode) atomicAdd(out, s * inv_B);
        else partial[blockIdx.x] = s;
    }
}

__global__ __launch_bounds__(BLOCK) void reduce_kernel(
    const float* __restrict__ partial, float* __restrict__ out,
    int n, float inv_B)
{
    const int tid = threadIdx.x;
    float s = 0.0f;
    for (int idx = tid; idx < n; idx += BLOCK) s += partial[idx];

    #pragma unroll
    for (int off = 32; off > 0; off >>= 1)
        s += __shfl_down(s, off, 64);

    __shared__ float wsum[4];
    int lane = tid & 63;
    int wid = tid >> 6;
    if (lane == 0) wsum[wid] = s;
    __syncthreads();
    if (tid == 0)
        out[0] = ((wsum[0] + wsum[1]) + (wsum[2] + wsum[3])) * inv_B;
}

extern "C" void kernel_launch(void* const* d_in, const int* in_sizes, int n_in,
                              void* d_out, int out_size, void* d_ws, size_t ws_size,
                              hipStream_t stream) {
    const float* pred = (const float*)d_in[0];
    const float* targ = (const float*)d_in[1];
    float* out = (float*)d_out;

    const int B = 16384;
    const float inv_B = 1.0f / (float)B;

    if (ws_size >= GRID * sizeof(float) && d_ws != nullptr) {
        float* partial = (float*)d_ws;
        yolo_loss_main<<<GRID, BLOCK, 0, stream>>>(pred, targ, partial, out, 0, inv_B);
        reduce_kernel<<<1, BLOCK, 0, stream>>>(partial, out, GRID, inv_B);
    } else {
        // fallback: atomic accumulation directly into out
        zero_out_kernel<<<1, 1, 0, stream>>>(out);
        yolo_loss_main<<<GRID, BLOCK, 0, stream>>>(pred, targ, nullptr, out, 1, inv_B);
    }
}

// Round 4
// 207.845 us; speedup vs baseline: 1.0164x; 1.0164x over previous
//
#include <hip/hip_runtime.h>

// YOLO v1 loss, B=16384, S=7, C=30. 192.7 MB read -> 1 float.
// Layout: pred[((b*S+i)*S+j)*30 + c]; i -> gi (x offset), j -> gj (y offset).
//
// v4: v0/v2/v3 all pinned at 72-77 us / ~1.3 TB/s HBM regardless of access
// pattern -> latency-bound with a tiny vmcnt window. Evidence: VGPR_Count=40..68
// vs a 120-float working set => compiler SANK the loads into consumption,
// keeping only ~4-8 outstanding loads/wave. Fix: load all 30 float4 into
// registers, then sched_barrier(0) so no load can be sunk past it; allow the
// register pressure explicitly via __launch_bounds__(256,3) (<=170 VGPR,
// 12 waves/CU). 12 waves x ~30 dwordx4 in flight ~= 360 lines/CU >> the ~145
// needed for 6.3 TB/s at HBM latency.

#define NS 7
#define NC 30
#define BLOCK 256
#define NPAIRS 401408               // 802816 cells / 2
#define GRID (NPAIRS / BLOCK)       // 1568 exact, no partial blocks

__global__ void zero_out_kernel(float* out) { out[0] = 0.0f; }

__device__ __forceinline__ float cell_loss(const float* __restrict__ p,
                                           const float* __restrict__ t,
                                           float gi, float gj)
{
    const float STEP = 1.0f / 7.0f;
    const float L_COORD = 5.0f;
    const float L_NOOBJ = 0.5f;

    // _convert_box for target, pred box1 (ch 0:4), pred box2 (ch 5:9)
    float ta, tb, tc, td;
    {
        float cx = (t[0] + gi) * STEP;
        float cy = (t[1] + gj) * STEP;
        ta = fmaxf(cx - t[2] * 0.5f, 0.0f);
        tb = fmaxf(cy - t[3] * 0.5f, 0.0f);
        tc = fminf(cx + t[2] * 0.5f, 1.0f);
        td = fminf(cy + t[3] * 0.5f, 1.0f);
    }
    float q1, w1, e1, r1;
    {
        float cx = (p[0] + gi) * STEP;
        float cy = (p[1] + gj) * STEP;
        q1 = fmaxf(cx - p[2] * 0.5f, 0.0f);
        w1 = fmaxf(cy - p[3] * 0.5f, 0.0f);
        e1 = fminf(cx + p[2] * 0.5f, 1.0f);
        r1 = fminf(cy + p[3] * 0.5f, 1.0f);
    }
    float q2, w2, e2, r2;
    {
        float cx = (p[5] + gi) * STEP;
        float cy = (p[6] + gj) * STEP;
        q2 = fmaxf(cx - p[7] * 0.5f, 0.0f);
        w2 = fmaxf(cy - p[8] * 0.5f, 0.0f);
        e2 = fminf(cx + p[7] * 0.5f, 1.0f);
        r2 = fminf(cy + p[8] * 0.5f, 1.0f);
    }

    float tarea = (td - tb) * (tc - ta);
    // _iou(tbox, pbox): inter NOT clamped; iou = inter>0 ? inter/(union+1e-5) : 0
    float iou1, iou2;
    {
        float minx = fmaxf(ta, q1), miny = fmaxf(tb, w1);
        float maxx = fminf(tc, e1), maxy = fminf(td, r1);
        float inter = (maxy - miny) * (maxx - minx);
        float uni = (e1 - q1) * (r1 - w1) + tarea - inter;
        iou1 = (inter > 0.0f) ? inter / (uni + 1e-5f) : 0.0f;
    }
    {
        float minx = fmaxf(ta, q2), miny = fmaxf(tb, w2);
        float maxx = fminf(tc, e2), maxy = fminf(td, r2);
        float inter = (maxy - miny) * (maxx - minx);
        float uni = (e2 - q2) * (r2 - w2) + tarea - inter;
        iou2 = (inter > 0.0f) ? inter / (uni + 1e-5f) : 0.0f;
    }

    bool sel2 = (iou1 <= iou2);
    float conf_t = sel2 ? iou2 : iou1;
    float px = sel2 ? p[5] : p[0];
    float py = sel2 ? p[6] : p[1];
    float pw = sel2 ? p[7] : p[2];
    float ph = sel2 ? p[8] : p[3];
    float pconf = sel2 ? p[9] : p[4];

    float obj = (t[4] > 0.0f) ? 1.0f : 0.0f;
    float noobj = (t[4] == 0.0f) ? 1.0f : 0.0f;

    float dx = px - t[0], dy = py - t[1];
    float dw = pw - t[2], dh = ph - t[3];
    float coord = dx * dx + dy * dy + dw * dw + dh * dh;

    float dc = pconf - conf_t;
    float obj_loss = dc * dc;

    float cls = 0.0f;
    #pragma unroll
    for (int k = 10; k < NC; ++k) {
        float d = p[k] - t[k];
        cls += d * d;
    }

    float d4 = p[4] - t[4];
    float d9 = p[9] - t[9];
    float noobj_loss = d4 * d4 + d9 * d9;

    return obj * (obj_loss + L_COORD * coord + cls) + L_NOOBJ * noobj * noobj_loss;
}

__global__ __launch_bounds__(BLOCK, 3) void yolo_loss_main(
    const float* __restrict__ pred,
    const float* __restrict__ targ,
    float* __restrict__ partial,
    float* __restrict__ out,
    int atomic_mode, float inv_B)
{
    const int tid = threadIdx.x;
    const int u = blockIdx.x * BLOCK + tid;   // pair index, NPAIRS total (exact)

    const float4* pg = (const float4*)pred + (size_t)u * 15;
    const float4* tg = (const float4*)targ + (size_t)u * 15;

    // ---- issue ALL 30 global_load_dwordx4 before any compute ----
    float4 A[15], B[15];
    #pragma unroll
    for (int k = 0; k < 15; ++k) A[k] = pg[k];
    #pragma unroll
    for (int k = 0; k < 15; ++k) B[k] = tg[k];
    // No instruction (in particular no load) may be scheduled across this:
    // pins all 30 loads ahead of the consumption stream -> full vmcnt window.
    __builtin_amdgcn_sched_barrier(0);

    float fp[60], ft[60];
    #pragma unroll
    for (int k = 0; k < 15; ++k) {
        fp[4 * k] = A[k].x; fp[4 * k + 1] = A[k].y;
        fp[4 * k + 2] = A[k].z; fp[4 * k + 3] = A[k].w;
        ft[4 * k] = B[k].x; ft[4 * k + 1] = B[k].y;
        ft[4 * k + 2] = B[k].z; ft[4 * k + 3] = B[k].w;
    }

    const int cellA = 2 * u;
    const int cellB = 2 * u + 1;
    const int jA = cellA % NS, iA = (cellA / NS) % NS;
    const int jB = cellB % NS, iB = (cellB / NS) % NS;

    float lsum = cell_loss(fp, ft, (float)iA, (float)jA)
               + cell_loss(fp + 30, ft + 30, (float)iB, (float)jB);

    // wave(64) shuffle reduce
    #pragma unroll
    for (int off = 32; off > 0; off >>= 1)
        lsum += __shfl_down(lsum, off, 64);

    __shared__ float wsum[4];
    int lane = tid & 63;
    int wid = tid >> 6;
    if (lane == 0) wsum[wid] = lsum;
    __syncthreads();
    if (tid == 0) {
        float s = (wsum[0] + wsum[1]) + (wsum[2] + wsum[3]);
        if (atomic_mode) atomicAdd(out, s * inv_B);
        else partial[blockIdx.x] = s;
    }
}

__global__ __launch_bounds__(BLOCK) void reduce_kernel(
    const float* __restrict__ partial, float* __restrict__ out,
    int n, float inv_B)
{
    const int tid = threadIdx.x;
    float s = 0.0f;
    for (int idx = tid; idx < n; idx += BLOCK) s += partial[idx];

    #pragma unroll
    for (int off = 32; off > 0; off >>= 1)
        s += __shfl_down(s, off, 64);

    __shared__ float wsum[4];
    int lane = tid & 63;
    int wid = tid >> 6;
    if (lane == 0) wsum[wid] = s;
    __syncthreads();
    if (tid == 0)
        out[0] = ((wsum[0] + wsum[1]) + (wsum[2] + wsum[3])) * inv_B;
}

extern "C" void kernel_launch(void* const* d_in, const int* in_sizes, int n_in,
                              void* d_out, int out_size, void* d_ws, size_t ws_size,
                              hipStream_t stream) {
    const float* pred = (const float*)d_in[0];
    const float* targ = (const float*)d_in[1];
    float* out = (float*)d_out;

    const int B = 16384;
    const float inv_B = 1.0f / (float)B;

    if (ws_size >= GRID * sizeof(float) && d_ws != nullptr) {
        float* partial = (float*)d_ws;
        yolo_loss_main<<<GRID, BLOCK, 0, stream>>>(pred, targ, partial, out, 0, inv_B);
        reduce_kernel<<<1, BLOCK, 0, stream>>>(partial, out, GRID, inv_B);
    } else {
        // fallback: atomic accumulation directly into out
        zero_out_kernel<<<1, 1, 0, stream>>>(out);
        yolo_loss_main<<<GRID, BLOCK, 0, stream>>>(pred, targ, nullptr, out, 1, inv_B);
    }
}